// Round 5
// baseline (201.194 us; speedup 1.0000x reference)
//
#include <hip/hip_runtime.h>
#include <math.h>

#define LAMBDA_DAG 0.5f

typedef unsigned int u32x4 __attribute__((ext_vector_type(4)));

// -------- K1: probs (transposed) + BCE partials + zero accumulators --------
__global__ void k_probs_bce(const float* __restrict__ logits,
                            const float* __restrict__ labels,
                            float* __restrict__ pT,        // [C*B]
                            float* __restrict__ bce_part,  // [gridDim.x]
                            float* __restrict__ per_term,  // [C] -> zeroed
                            float* __restrict__ npar,      // [C] -> zeroed
                            int* __restrict__ edge_cnt,    // [1] -> zeroed
                            int B, int C) {
    const int N = B * C;
    const int stride = gridDim.x * blockDim.x;
    const int t0 = blockIdx.x * blockDim.x + threadIdx.x;

    if (t0 == 0) edge_cnt[0] = 0;
    for (int i = t0; i < C; i += stride) { per_term[i] = 0.f; npar[i] = 0.f; }

    float accv = 0.f;
    for (int idx = t0; idx < N; idx += stride) {
        float l = logits[idx];
        float y = labels[idx];
        accv += fmaxf(l, 0.f) + log1pf(expf(-fabsf(l))) - l * y;
        float p = 1.f / (1.f + expf(-l));
        int b = idx / C;
        int c = idx - b * C;
        pT[(size_t)c * B + b] = p;
    }
    __shared__ float sdata[256];
    sdata[threadIdx.x] = accv;
    __syncthreads();
    for (int s = blockDim.x >> 1; s > 0; s >>= 1) {
        if (threadIdx.x < s) sdata[threadIdx.x] += sdata[threadIdx.x + s];
        __syncthreads();
    }
    if (threadIdx.x == 0) bce_part[blockIdx.x] = sdata[0];
}

// -------- K2: coalesced dag stream -> compact edge list --------
// Lane-contiguous float4 loads (1 KB per wave-instruction), 8 independent
// loads in flight per thread, nontemporal (dag is streamed once, don't cache).
#define LBUF_CAP 2048
__global__ void __launch_bounds__(256) k_dag_scan(
        const float* __restrict__ dag, int CC,
        int* __restrict__ edge_buf, int* __restrict__ edge_cnt) {
    __shared__ int lcnt, lbase;
    __shared__ int lbuf[LBUF_CAP];
    if (threadIdx.x == 0) lcnt = 0;
    __syncthreads();

    const int ng4 = CC >> 2;                    // float4 groups (CC % 4 == 0 here)
    const int tid = blockIdx.x * blockDim.x + threadIdx.x;
    const int nthreads = gridDim.x * blockDim.x;
    const u32x4* dag4 = (const u32x4*)dag;

    for (int g0 = tid; g0 < ng4; g0 += 8 * nthreads) {
        u32x4 v[8];
        int gi[8];
#pragma unroll
        for (int k = 0; k < 8; ++k) {
            gi[k] = g0 + k * nthreads;
            if (gi[k] < ng4)
                v[k] = __builtin_nontemporal_load(&dag4[gi[k]]);
            else
                v[k] = (u32x4){0u, 0u, 0u, 0u};
        }
#pragma unroll
        for (int k = 0; k < 8; ++k) {
            u32x4 d4 = v[k];
            if ((d4.x | d4.y | d4.z | d4.w) != 0u) {   // 1.0f = 0x3F800000
                int f0 = gi[k] * 4;
#pragma unroll
                for (int c = 0; c < 4; ++c) {
                    unsigned dv = (c == 0) ? d4.x : (c == 1) ? d4.y
                                : (c == 2) ? d4.z : d4.w;
                    if (dv != 0u) {
                        int slot = atomicAdd(&lcnt, 1);
                        if (slot < LBUF_CAP) lbuf[slot] = f0 + c;
                    }
                }
            }
        }
    }
    // scalar tail for CC % 4 (none for C=5000, but stay general)
    for (int f = (ng4 << 2) + tid; f < CC; f += nthreads) {
        if (dag[f] > 0.f) {
            int slot = atomicAdd(&lcnt, 1);
            if (slot < LBUF_CAP) lbuf[slot] = f;
        }
    }
    __syncthreads();
    int n = min(lcnt, LBUF_CAP);
    if (threadIdx.x == 0) lbase = atomicAdd(edge_cnt, n);
    __syncthreads();
    for (int t = threadIdx.x; t < n; t += blockDim.x)
        edge_buf[lbase + t] = lbuf[t];
}

// -------- K3: one wave per edge, coalesced gather + shuffle reduce --------
__global__ void __launch_bounds__(256) k_edges(
        const int* __restrict__ edge_buf, const int* __restrict__ edge_cnt,
        const float* __restrict__ pT,
        float* __restrict__ per_term, float* __restrict__ npar,
        int B, int C) {
    const int lane = threadIdx.x & 63;
    const int wid = (blockIdx.x * blockDim.x + threadIdx.x) >> 6;
    const int nw = (gridDim.x * blockDim.x) >> 6;
    const int ne = edge_cnt[0];
    for (int e = wid; e < ne; e += nw) {
        int f = edge_buf[e];
        int i = f / C;
        int j = f - i * C;
        float s = 0.f;
        for (int b = lane; b < B; b += 64) {
            float diff = fmaxf(pT[(size_t)i * B + b] - pT[(size_t)j * B + b], 0.f);
            s += diff * diff;
        }
#pragma unroll
        for (int off = 32; off > 0; off >>= 1)
            s += __shfl_down(s, off, 64);
        if (lane == 0) {
            atomicAdd(&per_term[i], s);
            atomicAdd(&npar[i], 1.f);
        }
    }
}

// -------- K4: final scalar reduction --------
__global__ void k_final(const float* __restrict__ per_term,
                        const float* __restrict__ npar,
                        const float* __restrict__ bce_part, int nb,
                        float* __restrict__ out, int B, int C) {
    float bs = 0.f, ps = 0.f, es = 0.f;
    for (int k = threadIdx.x; k < nb; k += blockDim.x) bs += bce_part[k];
    for (int i = threadIdx.x; i < C; i += blockDim.x) {
        float np = npar[i];
        es += np;
        if (np > 0.f) ps += per_term[i] / ((float)B * np);
    }
    __shared__ float s1[256], s2[256], s3[256];
    s1[threadIdx.x] = bs;
    s2[threadIdx.x] = ps;
    s3[threadIdx.x] = es;
    __syncthreads();
    for (int s = blockDim.x >> 1; s > 0; s >>= 1) {
        if (threadIdx.x < s) {
            s1[threadIdx.x] += s1[threadIdx.x + s];
            s2[threadIdx.x] += s2[threadIdx.x + s];
            s3[threadIdx.x] += s3[threadIdx.x + s];
        }
        __syncthreads();
    }
    if (threadIdx.x == 0) {
        float penalty = (s3[0] > 0.f) ? (s2[0] / s3[0]) : 0.f;
        out[0] = s1[0] / (float)(B * C) + LAMBDA_DAG * penalty;
    }
}

extern "C" void kernel_launch(void* const* d_in, const int* in_sizes, int n_in,
                              void* d_out, int out_size, void* d_ws, size_t ws_size,
                              hipStream_t stream) {
    const float* logits = (const float*)d_in[0];
    const float* labels = (const float*)d_in[1];
    const float* dag    = (const float*)d_in[2];
    float* out = (float*)d_out;

    const int C  = (int)(sqrt((double)in_sizes[2]) + 0.5);
    const int B  = in_sizes[0] / C;
    const int CC = in_sizes[2];

    float* ws       = (float*)d_ws;
    float* pT       = ws;                          // C*B floats (16B-aligned)
    float* per_term = pT + (size_t)C * B;          // C
    float* nparw    = per_term + C;                // C
    float* bce_part = nparw + C;                   // NB1
    const int NB1 = 320;
    int* edge_cnt   = (int*)(bce_part + NB1);      // 1 (+3 pad)
    int* edge_buf   = edge_cnt + 4;                // up to ~1M edges

    k_probs_bce<<<NB1, 256, 0, stream>>>(logits, labels, pT, bce_part,
                                         per_term, nparw, edge_cnt, B, C);

    // 8 float4 groups per thread, lane-contiguous
    const int ng4  = CC / 4;
    const int nblk = (ng4 + 8 * 256 - 1) / (8 * 256);
    k_dag_scan<<<nblk, 256, 0, stream>>>(dag, CC, edge_buf, edge_cnt);

    k_edges<<<512, 256, 0, stream>>>(edge_buf, edge_cnt, pT, per_term, nparw, B, C);

    k_final<<<1, 256, 0, stream>>>(per_term, nparw, bce_part, NB1, out, B, C);
}

// Round 6
// 199.357 us; speedup vs baseline: 1.0092x; 1.0092x over previous
//
#include <hip/hip_runtime.h>
#include <math.h>

#define LAMBDA_DAG 0.5f

typedef unsigned int u32x4 __attribute__((ext_vector_type(4)));

// -------- K1 (B==64 fast path): LDS-transpose probs + BCE + zero accum --------
__global__ void __launch_bounds__(256) k_probs_bce_t64(
        const float* __restrict__ logits, const float* __restrict__ labels,
        float* __restrict__ pT,            // [C*64]
        float* __restrict__ bce_part,      // [gridDim.x]
        float* __restrict__ per_term,      // [C] -> zeroed
        float* __restrict__ npar,          // [C] -> zeroed
        int* __restrict__ edge_cnt,        // [1] -> zeroed
        int C) {
    __shared__ float tile[64][65];         // +1 pad: conflict-free both phases
    const int lane = threadIdx.x & 63;
    const int wv   = threadIdx.x >> 6;     // 0..3
    const int c0   = blockIdx.x * 64;
    const int t0   = blockIdx.x * blockDim.x + threadIdx.x;
    const int stride = gridDim.x * blockDim.x;

    if (t0 == 0) edge_cnt[0] = 0;
    for (int i = t0; i < C; i += stride) { per_term[i] = 0.f; npar[i] = 0.f; }

    const int c = c0 + lane;
    const bool cv = (c < C);
    float accv = 0.f;
#pragma unroll 4
    for (int r = 0; r < 16; ++r) {
        const int b = wv * 16 + r;
        float l = cv ? logits[b * C + c] : 0.f;   // coalesced 256-B read
        float y = cv ? labels[b * C + c] : 0.f;
        if (cv) accv += fmaxf(l, 0.f) + log1pf(expf(-fabsf(l))) - l * y;
        tile[lane][b] = 1.f / (1.f + expf(-l));
    }
    __syncthreads();
#pragma unroll 4
    for (int r = 0; r < 16; ++r) {
        const int cl = wv * 16 + r;
        if (c0 + cl < C)
            pT[(size_t)(c0 + cl) * 64 + lane] = tile[cl][lane];  // coalesced write
    }
    __shared__ float sdata[256];
    sdata[threadIdx.x] = accv;
    __syncthreads();
    for (int s = 128; s > 0; s >>= 1) {
        if (threadIdx.x < s) sdata[threadIdx.x] += sdata[threadIdx.x + s];
        __syncthreads();
    }
    if (threadIdx.x == 0) bce_part[blockIdx.x] = sdata[0];
}

// -------- K1 (generic fallback, any B) --------
__global__ void k_probs_bce_gen(const float* __restrict__ logits,
                                const float* __restrict__ labels,
                                float* __restrict__ pT,
                                float* __restrict__ bce_part,
                                float* __restrict__ per_term,
                                float* __restrict__ npar,
                                int* __restrict__ edge_cnt,
                                int B, int C) {
    const int N = B * C;
    const int stride = gridDim.x * blockDim.x;
    const int t0 = blockIdx.x * blockDim.x + threadIdx.x;
    if (t0 == 0) edge_cnt[0] = 0;
    for (int i = t0; i < C; i += stride) { per_term[i] = 0.f; npar[i] = 0.f; }
    float accv = 0.f;
    for (int idx = t0; idx < N; idx += stride) {
        float l = logits[idx];
        float y = labels[idx];
        accv += fmaxf(l, 0.f) + log1pf(expf(-fabsf(l))) - l * y;
        float p = 1.f / (1.f + expf(-l));
        int b = idx / C;
        int c = idx - b * C;
        pT[(size_t)c * B + b] = p;
    }
    __shared__ float sdata[256];
    sdata[threadIdx.x] = accv;
    __syncthreads();
    for (int s = 128; s > 0; s >>= 1) {
        if (threadIdx.x < s) sdata[threadIdx.x] += sdata[threadIdx.x + s];
        __syncthreads();
    }
    if (threadIdx.x == 0) bce_part[blockIdx.x] = sdata[0];
}

// -------- K2: coalesced dag stream (regular loads, L3-friendly) -> edge list ----
#define LBUF_CAP 2048
__global__ void __launch_bounds__(256) k_dag_scan(
        const float* __restrict__ dag, int CC,
        int* __restrict__ edge_buf, int* __restrict__ edge_cnt) {
    __shared__ int lcnt, lbase;
    __shared__ int lbuf[LBUF_CAP];
    if (threadIdx.x == 0) lcnt = 0;
    __syncthreads();

    const int ng4 = CC >> 2;
    const int tid = blockIdx.x * blockDim.x + threadIdx.x;
    const int nthreads = gridDim.x * blockDim.x;
    const u32x4* dag4 = (const u32x4*)dag;

    for (int g0 = tid; g0 < ng4; g0 += 8 * nthreads) {
        u32x4 v[8];
        int gi[8];
#pragma unroll
        for (int k = 0; k < 8; ++k) {
            gi[k] = g0 + k * nthreads;
            v[k] = (gi[k] < ng4) ? dag4[gi[k]] : (u32x4){0u, 0u, 0u, 0u};
        }
#pragma unroll
        for (int k = 0; k < 8; ++k) {
            u32x4 d4 = v[k];
            if ((d4.x | d4.y | d4.z | d4.w) != 0u) {   // 1.0f = 0x3F800000
                int f0 = gi[k] * 4;
#pragma unroll
                for (int cc = 0; cc < 4; ++cc) {
                    unsigned dv = (cc == 0) ? d4.x : (cc == 1) ? d4.y
                                : (cc == 2) ? d4.z : d4.w;
                    if (dv != 0u) {
                        int slot = atomicAdd(&lcnt, 1);
                        if (slot < LBUF_CAP) lbuf[slot] = f0 + cc;
                    }
                }
            }
        }
    }
    for (int f = (ng4 << 2) + tid; f < CC; f += nthreads) {  // CC%4 tail
        if (dag[f] > 0.f) {
            int slot = atomicAdd(&lcnt, 1);
            if (slot < LBUF_CAP) lbuf[slot] = f;
        }
    }
    __syncthreads();
    int n = min(lcnt, LBUF_CAP);
    if (threadIdx.x == 0) lbase = atomicAdd(edge_cnt, n);
    __syncthreads();
    for (int t = threadIdx.x; t < n; t += blockDim.x)
        edge_buf[lbase + t] = lbuf[t];
}

// -------- K3: one wave per edge, coalesced gather + shuffle reduce --------
__global__ void __launch_bounds__(256) k_edges(
        const int* __restrict__ edge_buf, const int* __restrict__ edge_cnt,
        const float* __restrict__ pT,
        float* __restrict__ per_term, float* __restrict__ npar,
        int B, int C) {
    const int lane = threadIdx.x & 63;
    const int wid = (blockIdx.x * blockDim.x + threadIdx.x) >> 6;
    const int nw = (gridDim.x * blockDim.x) >> 6;
    const int ne = edge_cnt[0];
    for (int e = wid; e < ne; e += nw) {
        int f = edge_buf[e];
        int i = f / C;
        int j = f - i * C;
        float s = 0.f;
        for (int b = lane; b < B; b += 64) {
            float diff = fmaxf(pT[(size_t)i * B + b] - pT[(size_t)j * B + b], 0.f);
            s += diff * diff;
        }
#pragma unroll
        for (int off = 32; off > 0; off >>= 1)
            s += __shfl_down(s, off, 64);
        if (lane == 0) {
            atomicAdd(&per_term[i], s);
            atomicAdd(&npar[i], 1.f);
        }
    }
}

// -------- K4: final scalar reduction --------
__global__ void k_final(const float* __restrict__ per_term,
                        const float* __restrict__ npar,
                        const float* __restrict__ bce_part, int nb,
                        float* __restrict__ out, int B, int C) {
    float bs = 0.f, ps = 0.f, es = 0.f;
    for (int k = threadIdx.x; k < nb; k += blockDim.x) bs += bce_part[k];
    for (int i = threadIdx.x; i < C; i += blockDim.x) {
        float np = npar[i];
        es += np;
        if (np > 0.f) ps += per_term[i] / ((float)B * np);
    }
    __shared__ float s1[256], s2[256], s3[256];
    s1[threadIdx.x] = bs;
    s2[threadIdx.x] = ps;
    s3[threadIdx.x] = es;
    __syncthreads();
    for (int s = 128; s > 0; s >>= 1) {
        if (threadIdx.x < s) {
            s1[threadIdx.x] += s1[threadIdx.x + s];
            s2[threadIdx.x] += s2[threadIdx.x + s];
            s3[threadIdx.x] += s3[threadIdx.x + s];
        }
        __syncthreads();
    }
    if (threadIdx.x == 0) {
        float penalty = (s3[0] > 0.f) ? (s2[0] / s3[0]) : 0.f;
        out[0] = s1[0] / (float)(B * C) + LAMBDA_DAG * penalty;
    }
}

extern "C" void kernel_launch(void* const* d_in, const int* in_sizes, int n_in,
                              void* d_out, int out_size, void* d_ws, size_t ws_size,
                              hipStream_t stream) {
    const float* logits = (const float*)d_in[0];
    const float* labels = (const float*)d_in[1];
    const float* dag    = (const float*)d_in[2];
    float* out = (float*)d_out;

    const int C  = (int)(sqrt((double)in_sizes[2]) + 0.5);
    const int B  = in_sizes[0] / C;
    const int CC = in_sizes[2];

    float* ws       = (float*)d_ws;
    float* pT       = ws;                          // C*B floats (16B-aligned)
    float* per_term = pT + (size_t)C * B;          // C
    float* nparw    = per_term + C;                // C
    float* bce_part = nparw + C;                   // up to 320
    const int NBMAX = 320;
    int* edge_cnt   = (int*)(bce_part + NBMAX);    // 1 (+3 pad)
    int* edge_buf   = edge_cnt + 4;                // up to ~1M edges

    int nb;
    if (B == 64) {
        nb = (C + 63) / 64;                        // 79 for C=5000
        k_probs_bce_t64<<<nb, 256, 0, stream>>>(logits, labels, pT, bce_part,
                                                per_term, nparw, edge_cnt, C);
    } else {
        nb = NBMAX;
        k_probs_bce_gen<<<nb, 256, 0, stream>>>(logits, labels, pT, bce_part,
                                                per_term, nparw, edge_cnt, B, C);
    }

    const int ng4  = CC / 4;
    const int nblk = (ng4 + 8 * 256 - 1) / (8 * 256);
    k_dag_scan<<<nblk, 256, 0, stream>>>(dag, CC, edge_buf, edge_cnt);

    k_edges<<<1024, 256, 0, stream>>>(edge_buf, edge_cnt, pT, per_term, nparw, B, C);

    k_final<<<1, 256, 0, stream>>>(per_term, nparw, bce_part, nb, out, B, C);
}